// Round 3
// baseline (226.476 us; speedup 1.0000x reference)
//
#include <hip/hip_runtime.h>
#include <math.h>
#include <stdint.h>

// VocosISTFTHead on MI355X.
//  K0 convert_B  : W (1026x512 f32) -> tiled bf16 hi/lo planes [y8][kt16][r128][k32]
//  K1 gemm_mfma  : spec = hs @ W.T + b via bf16-split MFMA (Ah*Bh + Al*Bh + Ah*Bl),
//                  256x128 tile, 8 waves (4Mx2N), LDS double-buffer, 1 barrier/K-step,
//                  stage-before-compute (T3 2-phase), setprio (T5), XCD swizzle (T1).
//                  Nyquist pair (cols 512/1025) folded into y==7 blocks as VALU dots.
//                  Fused epilogue -> complex coeffs (exp/clamp, cos/sin).
//  K2 fft_win    : 1024-pt real iFFT per frame (512-pt complex Stockham radix-8) * window
//  K3 gather_out : deterministic overlap-add gather + window^2 normalization
// ws: coeffs/frames 32768x1028 f32 (134.7MB) | Bhi 1MB | Blo 1MB

#define RS      1028
#define FRAMES  32768
#define TWO_PI  6.283185307179586f

typedef unsigned short ushort_t;
typedef __attribute__((ext_vector_type(8)))  short bf16x8;
typedef __attribute__((ext_vector_type(16))) float f32x16;

#define GLDS(gp, lp) __builtin_amdgcn_global_load_lds( \
    (const __attribute__((address_space(1))) void*)(gp), \
    (__attribute__((address_space(3))) void*)(lp), 16, 0, 0)

__device__ __forceinline__ float2 f2(float x, float y){ return make_float2(x,y); }
__device__ __forceinline__ float2 cadd(float2 a, float2 b){ return f2(a.x+b.x, a.y+b.y); }
__device__ __forceinline__ float2 csub(float2 a, float2 b){ return f2(a.x-b.x, a.y-b.y); }
__device__ __forceinline__ float2 cmul(float2 a, float2 b){ return f2(a.x*b.x - a.y*b.y, a.x*b.y + a.y*b.x); }

// ---------------------------------------------------------------------------
// K0: W -> tiled bf16 hi/lo planes. [y(8)][kt(16)][r(128)][k(32)],
// tile rows 0-63 = magnitude rows (p = y*64+r), 64-127 = phase rows (513+p).
// ---------------------------------------------------------------------------
__global__ __launch_bounds__(256) void convert_B(
    const float* __restrict__ Wm, ushort_t* __restrict__ Bhi, ushort_t* __restrict__ Blo)
{
  const int gid = blockIdx.x * 256 + threadIdx.x;    // 65536 granules of 8
  const int sd = gid & 3;
  const int r  = (gid >> 2) & 127;
  const int kt = (gid >> 9) & 15;
  const int y  = gid >> 13;                          // 0..7
  const int srow = (r < 64) ? (y*64 + r) : (513 + y*64 + (r - 64));
  const float* src = Wm + (size_t)srow * 512 + kt*32 + sd*8;
  const float4 a = *(const float4*)src;
  const float4 b = *(const float4*)(src + 4);
  const float v[8] = {a.x,a.y,a.z,a.w,b.x,b.y,b.z,b.w};
  uint32_t hi[4], lo[4];
  #pragma unroll
  for (int i = 0; i < 4; ++i) {
    const uint32_t b0 = __float_as_uint(v[2*i]), b1 = __float_as_uint(v[2*i+1]);
    hi[i] = (b0 >> 16) | (b1 & 0xFFFF0000u);
    const float f0 = v[2*i]   - __uint_as_float(b0 & 0xFFFF0000u);
    const float f1 = v[2*i+1] - __uint_as_float(b1 & 0xFFFF0000u);
    lo[i] = (__float_as_uint(f0) >> 16) | (__float_as_uint(f1) & 0xFFFF0000u);
  }
  const size_t off = (size_t)gid * 8;
  *(uint4*)(Bhi + off) = make_uint4(hi[0], hi[1], hi[2], hi[3]);
  *(uint4*)(Blo + off) = make_uint4(lo[0], lo[1], lo[2], lo[3]);
}

// ---------------------------------------------------------------------------
// K1: MFMA GEMM, 256 rows x 64 col-pairs per block, 512 threads.
// ---------------------------------------------------------------------------
__global__ __launch_bounds__(512) void gemm_mfma(
    const float* __restrict__ hs, const ushort_t* __restrict__ Bhi,
    const ushort_t* __restrict__ Blo, const float* __restrict__ Wm,
    const float* __restrict__ bias, float* __restrict__ coeffs)
{
  __shared__ float    Ab[2][256*32];     // 2 x 32KB, granule sd = slot ^ (r&7)
  __shared__ ushort_t Bh[2][128*32];     // 2 x 8KB,  granule sd = slot ^ ((r>>1)&3)
  __shared__ ushort_t Bl[2][128*32];     // 2 x 8KB

  const int tid = threadIdx.x;
  const int w = tid >> 6, l = tid & 63;
  const int wr = w >> 1, wc = w & 1;     // wave grid 4M x 2N
  const int lr = l & 31, lh = l >> 5;

  const int bid = blockIdx.x;                        // 1024 = 8 XCD * 128
  const int swz = (bid & 7) * 128 + (bid >> 3);      // bijective
  const int mb = swz >> 3, y = swz & 7;              // 9 (well, 8) y per mb chunk

  // A staging sources (per-lane, inverse-swizzled)
  const float* pa[4];
  #pragma unroll
  for (int ch = 0; ch < 4; ++ch) {
    const int g = ch*512 + w*64 + l;                 // granule 0..2047
    const int r = g >> 3, sd = g & 7;
    const int sl = sd ^ (r & 7);
    pa[ch] = hs + (size_t)(mb*256 + r) * 512 + sl*4;
  }
  // B staging sources
  const ushort_t *pbh, *pbl;
  {
    const int g = w*64 + l;                          // granule 0..511
    const int r = g >> 2, sd = g & 3;
    const int sl = sd ^ ((r >> 1) & 3);
    const size_t off = (size_t)y*65536 + r*32 + sl*8;
    pbh = Bhi + off; pbl = Blo + off;
  }

  f32x16 acc[2][2];
  #pragma unroll
  for (int rf = 0; rf < 2; ++rf)
    #pragma unroll
    for (int cf = 0; cf < 2; ++cf)
      #pragma unroll
      for (int q = 0; q < 16; ++q) acc[rf][cf][q] = 0.f;

  // Nyquist fold: y==7 blocks, waves 0-3, one row per thread.
  const bool nyq = (y == 7) && (tid < 256);
  float dm = 0.f, dp = 0.f;
  const int nr = tid & 255;
  const float* wmag = Wm + (size_t)512  * 512;
  const float* wph  = Wm + (size_t)1025 * 512;

  // prologue: stage kt=0 into buf 0
  #pragma unroll
  for (int ch = 0; ch < 4; ++ch) GLDS(pa[ch], &Ab[0][(ch*512 + w*64)*4]);
  GLDS(pbh, &Bh[0][(w*64)*8]);
  GLDS(pbl, &Bl[0][(w*64)*8]);
  __syncthreads();

  int cur = 0;
  for (int kt = 0; kt < 16; ++kt) {
    const int nxt = cur ^ 1;
    #pragma unroll
    for (int kh = 0; kh < 2; ++kh) {
      // issue half of next-tile staging (latency hides under this phase's MFMA)
      if (kt < 15) {
        const int kk = (kt + 1) * 32;
        GLDS(pa[kh*2+0] + kk, &Ab[nxt][((kh*2+0)*512 + w*64)*4]);
        GLDS(pa[kh*2+1] + kk, &Ab[nxt][((kh*2+1)*512 + w*64)*4]);
        if (kh == 0) GLDS(pbh + (size_t)(kt+1)*4096, &Bh[nxt][(w*64)*8]);
        else         GLDS(pbl + (size_t)(kt+1)*4096, &Bl[nxt][(w*64)*8]);
      }
      // B fragments: cf=0 mag (rows 0-63), cf=1 phase (rows 64-127)
      bf16x8 fbh[2], fbl[2];
      #pragma unroll
      for (int cf = 0; cf < 2; ++cf) {
        const int r = cf*64 + wc*32 + lr;
        const int sw2 = (kh*2 + lh) ^ ((r >> 1) & 3);
        fbh[cf] = *(const bf16x8*)(&Bh[cur][r*32 + sw2*8]);
        fbl[cf] = *(const bf16x8*)(&Bl[cur][r*32 + sw2*8]);
      }
      // A fragments: f32 -> bf16 hi/lo split in-register
      union { uint32_t u[4]; bf16x8 v; } Ah[2], Al[2];
      #pragma unroll
      for (int rf = 0; rf < 2; ++rf) {
        const int ar = wr*64 + rf*32 + lr;
        const int s0 = kh*4 + lh*2;
        const float4 a0 = *(const float4*)(&Ab[cur][ar*32 + ((s0    ) ^ (ar & 7))*4]);
        const float4 a1 = *(const float4*)(&Ab[cur][ar*32 + ((s0 + 1) ^ (ar & 7))*4]);
        const float av[8] = {a0.x,a0.y,a0.z,a0.w,a1.x,a1.y,a1.z,a1.w};
        #pragma unroll
        for (int i = 0; i < 4; ++i) {
          const uint32_t b0 = __float_as_uint(av[2*i]), b1 = __float_as_uint(av[2*i+1]);
          Ah[rf].u[i] = (b0 >> 16) | (b1 & 0xFFFF0000u);
          const float f0 = av[2*i]   - __uint_as_float(b0 & 0xFFFF0000u);
          const float f1 = av[2*i+1] - __uint_as_float(b1 & 0xFFFF0000u);
          Al[rf].u[i] = (__float_as_uint(f0) >> 16) | (__float_as_uint(f1) & 0xFFFF0000u);
        }
      }
      __builtin_amdgcn_s_setprio(1);
      #pragma unroll
      for (int rf = 0; rf < 2; ++rf)
        #pragma unroll
        for (int cf = 0; cf < 2; ++cf) {
          acc[rf][cf] = __builtin_amdgcn_mfma_f32_32x32x16_bf16(Ah[rf].v, fbh[cf], acc[rf][cf], 0, 0, 0);
          acc[rf][cf] = __builtin_amdgcn_mfma_f32_32x32x16_bf16(Al[rf].v, fbh[cf], acc[rf][cf], 0, 0, 0);
          acc[rf][cf] = __builtin_amdgcn_mfma_f32_32x32x16_bf16(Ah[rf].v, fbl[cf], acc[rf][cf], 0, 0, 0);
        }
      __builtin_amdgcn_s_setprio(0);
    }
    // Nyquist dots stream the f32 A tile (exact, overlaps MFMA pipe)
    if (nyq) {
      #pragma unroll
      for (int j = 0; j < 8; ++j) {
        const float4 av = *(const float4*)(&Ab[cur][nr*32 + (j ^ (nr & 7))*4]);
        const float4 m4 = *(const float4*)(wmag + kt*32 + j*4);
        const float4 p4 = *(const float4*)(wph  + kt*32 + j*4);
        dm = fmaf(av.x,m4.x,fmaf(av.y,m4.y,fmaf(av.z,m4.z,fmaf(av.w,m4.w,dm))));
        dp = fmaf(av.x,p4.x,fmaf(av.y,p4.y,fmaf(av.z,p4.z,fmaf(av.w,p4.w,dp))));
      }
    }
    __syncthreads();      // drains vmcnt (stage done) + lgkm (reads done)
    cur = nxt;
  }

  // Epilogue: acc[rf][0]=mag, acc[rf][1]=phase, same lane->(row,col) map.
  // C/D: col = lane&31, row = (q&3) + 8*(q>>2) + 4*(lane>>5).
  const int pcol = y*64 + wc*32 + lr;                // always < 512
  const float bm = bias[pcol], bp = bias[513 + pcol];
  #pragma unroll
  for (int rf = 0; rf < 2; ++rf) {
    #pragma unroll
    for (int q = 0; q < 16; ++q) {
      const int rl = (q & 3) + 8*(q >> 2) + 4*lh;
      const int f  = mb*256 + wr*64 + rf*32 + rl;
      const float sm = acc[rf][0][q] + bm;
      const float sp = acc[rf][1][q] + bp;
      const float mag = fminf(__expf(sm), 100.0f);
      float aa = mag * __cosf(sp);
      float bb = mag * __sinf(sp);
      if (pcol == 0) bb = 0.f;                       // DC imag
      *(float2*)(coeffs + (size_t)f * RS + 2*pcol) = make_float2(aa, bb);
    }
  }
  if (nyq) {
    const float sm = dm + bias[512];
    const float sp = dp + bias[1025];
    const float mag = fminf(__expf(sm), 100.0f);
    *(float2*)(coeffs + (size_t)(mb*256 + nr) * RS + 1024) =
        make_float2(mag * __cosf(sp), 0.f);          // Nyquist imag = 0
  }
}

// ---------------------------------------------------------------------------
// K2: per-frame irfft(1024) + window (unchanged, verified).
// ---------------------------------------------------------------------------
#define PIDX(s) ((s) + ((s) >> 3))

template<int NS>
__device__ __forceinline__ void stage_fft(const float2* in, float2* out, int l)
{
  float2 v[8];
  #pragma unroll
  for (int r = 0; r < 8; ++r) v[r] = in[PIDX(l + 64*r)];
  if (NS > 1) {
    const float ang = TWO_PI * (float)(l & (NS-1)) / (float)(NS * 8);
    float sn, cs; __sincosf(ang, &sn, &cs);
    const float2 wb = f2(cs, sn);
    float2 cur = wb;
    #pragma unroll
    for (int r = 1; r < 8; ++r) { v[r] = cmul(v[r], cur); cur = cmul(cur, wb); }
  }
  const float2 e0=v[0], e1=v[2], e2=v[4], e3=v[6];
  const float2 o0=v[1], o1=v[3], o2=v[5], o3=v[7];
  float2 a = cadd(e0,e2), b = csub(e0,e2), c = cadd(e1,e3), d = csub(e1,e3);
  const float2 E0 = cadd(a,c), E2 = csub(a,c);
  const float2 E1 = f2(b.x - d.y, b.y + d.x), E3 = f2(b.x + d.y, b.y - d.x);
  a = cadd(o0,o2); b = csub(o0,o2); c = cadd(o1,o3); d = csub(o1,o3);
  const float2 O0 = cadd(a,c), O2 = csub(a,c);
  const float2 O1 = f2(b.x - d.y, b.y + d.x), O3 = f2(b.x + d.y, b.y - d.x);
  const float r2 = 0.70710678118654752f;
  const float2 t0 = O0;
  const float2 t1 = f2(r2*(O1.x - O1.y),  r2*(O1.x + O1.y));
  const float2 t2 = f2(-O2.y, O2.x);
  const float2 t3 = f2(-r2*(O3.x + O3.y), r2*(O3.x - O3.y));
  float2 X[8];
  X[0]=cadd(E0,t0); X[4]=csub(E0,t0);
  X[1]=cadd(E1,t1); X[5]=csub(E1,t1);
  X[2]=cadd(E2,t2); X[6]=csub(E2,t2);
  X[3]=cadd(E3,t3); X[7]=csub(E3,t3);
  const int idxD = (l / NS) * (NS * 8) + (l & (NS-1));
  #pragma unroll
  for (int q = 0; q < 8; ++q) out[PIDX(idxD + q*NS)] = X[q];
}

__global__ __launch_bounds__(256) void fft_win(
    const float* coeffs, float* frames, const float* __restrict__ window)
{
  __shared__ float2 bA[4][576];
  __shared__ float2 bB[4][576];
  const int tid = threadIdx.x;
  const int w = tid >> 6, l = tid & 63;
  const size_t f = (size_t)blockIdx.x * 4 + w;
  const float* crow = coeffs + f * RS;
  const float sc = 1.0f / 1024.0f;
  const float a512 = crow[1024];

  #pragma unroll
  for (int j = 0; j < 4; ++j) {
    const int k = 1 + l + 64*j;
    const float2 Ck = *(const float2*)(crow + 2*k);
    const float2 Cq = *(const float2*)(crow + 2*(512-k));
    float sn, cs; __sincosf(TWO_PI * (1.0f/1024.0f) * (float)k, &sn, &cs);
    const float Ex = sc*(Ck.x + Cq.x), Ey = sc*(Ck.y - Cq.y);
    const float Dx = Ck.x - Cq.x,      Dy = Ck.y + Cq.y;
    const float Ox = sc*(cs*Dx - sn*Dy), Oy = sc*(cs*Dy + sn*Dx);
    bA[w][PIDX(k)]     = f2(Ex - Oy, Ey + Ox);
    bA[w][PIDX(512-k)] = f2(Ex + Oy, Ox - Ey);
  }
  if (l == 0) {
    const float a0 = crow[0];
    bA[w][PIDX(0)] = f2(sc*(a0 + a512), sc*(a0 - a512));
  }
  __syncthreads();
  stage_fft<1 >(bA[w], bB[w], l);
  __syncthreads();
  stage_fft<8 >(bB[w], bA[w], l);
  __syncthreads();
  stage_fft<64>(bA[w], bB[w], l);
  __syncthreads();

  float* frow = frames + f * RS;
  #pragma unroll
  for (int j = 0; j < 8; ++j) {
    const int m = l + 64*j;
    const float2 z  = bB[w][PIDX(m)];
    const float2 wv = *(const float2*)(window + 2*m);
    *(float2*)(frow + 2*m) = f2(z.x * wv.x, z.y * wv.y);
  }
}

// ---------------------------------------------------------------------------
// K3: overlap-add gather + normalization (unchanged, verified).
// ---------------------------------------------------------------------------
__global__ __launch_bounds__(256) void gather_out(
    const float* __restrict__ frames, const float* __restrict__ window,
    float* __restrict__ out)
{
  const int idx = blockIdx.x * 256 + threadIdx.x;
  const int b  = idx >> 19;
  const int jj = idx & 524287;
  const int s  = jj + 384;
  int tlo = (s - 768) >> 8; if (tlo < 0) tlo = 0;
  int thi = s >> 8;         if (thi > 2047) thi = 2047;
  float acc = 0.f, nrm = 0.f;
  for (int t = tlo; t <= thi; ++t) {
    const int n = s - (t << 8);
    const float wv = window[n];
    nrm = fmaf(wv, wv, nrm);
    acc += frames[(size_t)(b * 2048 + t) * RS + n];
  }
  out[idx] = acc / nrm;
}

// ---------------------------------------------------------------------------
extern "C" void kernel_launch(void* const* d_in, const int* in_sizes, int n_in,
                              void* d_out, int out_size, void* d_ws, size_t ws_size,
                              hipStream_t stream)
{
  const float* hs     = (const float*)d_in[0];   // (16,2048,512)
  const float* Wm     = (const float*)d_in[1];   // (1026,512)
  const float* bias   = (const float*)d_in[2];   // (1026,)
  const float* window = (const float*)d_in[3];   // (1024,)

  float* buf = (float*)d_ws;                                   // 134,742,016 B
  ushort_t* Bhi = (ushort_t*)((char*)d_ws + 134742016);        // 1,048,576 B
  ushort_t* Blo = Bhi + 8*16*4096;                             // 1,048,576 B

  convert_B<<<256, 256, 0, stream>>>(Wm, Bhi, Blo);
  gemm_mfma<<<1024, 512, 0, stream>>>(hs, Bhi, Blo, Wm, bias, buf);
  fft_win<<<FRAMES / 4, 256, 0, stream>>>(buf, buf, window);
  gather_out<<<8388608 / 256, 256, 0, stream>>>(buf, window, (float*)d_out);
}

// Round 4
// 209.741 us; speedup vs baseline: 1.0798x; 1.0798x over previous
//
#include <hip/hip_runtime.h>
#include <math.h>
#include <stdint.h>

// VocosISTFTHead on MI355X.
//  K0 convert_B  : W (1026x512 f32) -> tiled bf16 hi/lo planes [yb4][kt16][r256][k32]
//  K1 gemm_mfma  : spec = hs @ W.T + b via bf16-split MFMA (Ah*Bh + Al*Bh + Ah*Bl),
//                  16x16x32 shape (16-row frag reads = bank-optimal LDS),
//                  block 256 rows x 128 pairs, 8 waves (2M x 4N), wave = 128x64,
//                  double-buffered LDS, stage-before-compute, 1 barrier/K-step.
//                  Nyquist pair (cols 512/1025) folded into yb==3 blocks (VALU dots).
//                  Fused epilogue -> complex coeffs (exp/clamp, cos/sin).
//  K2 fft_win    : 1024-pt real iFFT per frame (512-pt complex Stockham radix-8) * window
//  K3 gather_out : deterministic overlap-add gather + window^2 normalization
// ws: coeffs/frames 32768x1028 f32 (134.7MB) | Bhi 1MB | Blo 1MB

#define RS      1028
#define FRAMES  32768
#define TWO_PI  6.283185307179586f

typedef unsigned short ushort_t;
typedef __attribute__((ext_vector_type(8))) short bf16x8;
typedef __attribute__((ext_vector_type(4))) float f32x4;

#define GLDS(gp, lp) __builtin_amdgcn_global_load_lds( \
    (const __attribute__((address_space(1))) void*)(gp), \
    (__attribute__((address_space(3))) void*)(lp), 16, 0, 0)

__device__ __forceinline__ float2 f2(float x, float y){ return make_float2(x,y); }
__device__ __forceinline__ float2 cadd(float2 a, float2 b){ return f2(a.x+b.x, a.y+b.y); }
__device__ __forceinline__ float2 csub(float2 a, float2 b){ return f2(a.x-b.x, a.y-b.y); }
__device__ __forceinline__ float2 cmul(float2 a, float2 b){ return f2(a.x*b.x - a.y*b.y, a.x*b.y + a.y*b.x); }

// ---------------------------------------------------------------------------
// K0: W -> tiled bf16 hi/lo planes. [yb(4)][kt(16)][r(256)][k(32)], unswizzled.
// Tile rows 0-127 = magnitude rows (W row p = yb*128+r), 128-255 = phase (513+p).
// ---------------------------------------------------------------------------
__global__ __launch_bounds__(256) void convert_B(
    const float* __restrict__ Wm, ushort_t* __restrict__ Bhi, ushort_t* __restrict__ Blo)
{
  const int gid = blockIdx.x * 256 + threadIdx.x;    // 65536 granules of 8 elems
  const int sd = gid & 3;
  const int r  = (gid >> 2) & 255;
  const int kt = (gid >> 10) & 15;
  const int yb = gid >> 14;                          // 0..3
  const int srow = (r < 128) ? (yb*128 + r) : (513 + yb*128 + (r - 128));
  const float* src = Wm + (size_t)srow * 512 + kt*32 + sd*8;
  const float4 a = *(const float4*)src;
  const float4 b = *(const float4*)(src + 4);
  const float v[8] = {a.x,a.y,a.z,a.w,b.x,b.y,b.z,b.w};
  uint32_t hi[4], lo[4];
  #pragma unroll
  for (int i = 0; i < 4; ++i) {
    const uint32_t b0 = __float_as_uint(v[2*i]), b1 = __float_as_uint(v[2*i+1]);
    hi[i] = (b0 >> 16) | (b1 & 0xFFFF0000u);
    const float f0 = v[2*i]   - __uint_as_float(b0 & 0xFFFF0000u);
    const float f1 = v[2*i+1] - __uint_as_float(b1 & 0xFFFF0000u);
    lo[i] = (__float_as_uint(f0) >> 16) | (__float_as_uint(f1) & 0xFFFF0000u);
  }
  const size_t off = (size_t)gid * 8;
  *(uint4*)(Bhi + off) = make_uint4(hi[0], hi[1], hi[2], hi[3]);
  *(uint4*)(Blo + off) = make_uint4(lo[0], lo[1], lo[2], lo[3]);
}

// ---------------------------------------------------------------------------
// K1: MFMA GEMM, 256 rows x 128 col-pairs per block, 512 threads (8 waves).
// ---------------------------------------------------------------------------
__global__ __launch_bounds__(512, 2) void gemm_mfma(
    const float* __restrict__ hs, const ushort_t* __restrict__ Bhi,
    const ushort_t* __restrict__ Blo, const float* __restrict__ Wm,
    const float* __restrict__ bias, float* __restrict__ coeffs)
{
  __shared__ float    Ab[2][8192];     // 2 x 32KB: [r256][k32] f32, slot^(r&7)
  __shared__ ushort_t Bh[2][8192];     // 2 x 16KB: [r256][k32] bf16, slot^((r>>1)&3)
  __shared__ ushort_t Bl[2][8192];     // 2 x 16KB

  const int tid = threadIdx.x;
  const int w = tid >> 6, l = tid & 63;
  const int wr = w >> 2, wc = w & 3;         // wave grid 2M x 4N
  const int lc = l & 15, kg = l >> 4;        // frag row/col = lc, k-group = kg

  const int bid = blockIdx.x;                // 512 = 8 XCD * 64
  const int swz = (bid & 7) * 64 + (bid >> 3);
  const int mb = swz >> 2, yb = swz & 3;     // 4 consecutive yb per mb per XCD

  // A staging sources (per-lane, inverse-swizzled): granule(r, sd), sd = sl ^ (r&7)
  const float* pa[4];
  #pragma unroll
  for (int ch = 0; ch < 4; ++ch) {
    const int g = ch*512 + w*64 + l;         // 0..2047
    const int r = g >> 3, sd = g & 7;
    const int sl = sd ^ (r & 7);
    pa[ch] = hs + (size_t)(mb*256 + r) * 512 + sl*4;
  }
  // B staging sources: granule(r, sd), sd = sl ^ ((r>>1)&3)
  const ushort_t *pbh[2], *pbl[2];
  #pragma unroll
  for (int ch = 0; ch < 2; ++ch) {
    const int g = ch*512 + w*64 + l;         // 0..1023
    const int r = g >> 2, sd = g & 3;
    const int sl = sd ^ ((r >> 1) & 3);
    const size_t off = (size_t)yb*131072 + r*32 + sl*8;
    pbh[ch] = Bhi + off; pbl[ch] = Blo + off;
  }

  f32x4 acc[8][4];                           // [rf][cf]: cf 0,1 mag; 2,3 phase
  #pragma unroll
  for (int rf = 0; rf < 8; ++rf)
    #pragma unroll
    for (int cf = 0; cf < 4; ++cf)
      #pragma unroll
      for (int q = 0; q < 4; ++q) acc[rf][cf][q] = 0.f;

  // Nyquist fold: yb==3 blocks, threads 0-255, one row each.
  const bool nyq = (yb == 3) && (tid < 256);
  float dm = 0.f, dp = 0.f;
  const int nr = tid & 255;
  const float* wmag = Wm + (size_t)512  * 512;
  const float* wph  = Wm + (size_t)1025 * 512;

  // prologue: stage kt=0 into buf 0
  #pragma unroll
  for (int ch = 0; ch < 4; ++ch) GLDS(pa[ch], &Ab[0][(ch*512 + w*64)*4]);
  #pragma unroll
  for (int ch = 0; ch < 2; ++ch) {
    GLDS(pbh[ch], &Bh[0][(ch*512 + w*64)*8]);
    GLDS(pbl[ch], &Bl[0][(ch*512 + w*64)*8]);
  }
  __syncthreads();

  int cur = 0;
  for (int kt = 0; kt < 16; ++kt) {
    const int nxt = cur ^ 1;
    // issue next-tile staging first; latency hides under this step's MFMA
    if (kt < 15) {
      const int kk = (kt + 1) * 32;
      const size_t bko = (size_t)(kt + 1) * 8192;
      #pragma unroll
      for (int ch = 0; ch < 4; ++ch) GLDS(pa[ch] + kk, &Ab[nxt][(ch*512 + w*64)*4]);
      #pragma unroll
      for (int ch = 0; ch < 2; ++ch) {
        GLDS(pbh[ch] + bko, &Bh[nxt][(ch*512 + w*64)*8]);
        GLDS(pbl[ch] + bko, &Bl[nxt][(ch*512 + w*64)*8]);
      }
    }
    // B fragments: one b128 per frag per plane (16-row reads: bank-optimal)
    bf16x8 fbh[4], fbl[4];
    #pragma unroll
    for (int cf = 0; cf < 4; ++cf) {
      const int r = ((cf < 2) ? 0 : 128) + wc*32 + (cf & 1)*16 + lc;
      const int slot = kg ^ ((r >> 1) & 3);
      fbh[cf] = *(const bf16x8*)(&Bh[cur][r*32 + slot*8]);
      fbl[cf] = *(const bf16x8*)(&Bl[cur][r*32 + slot*8]);
    }
    // two rf-halves to bound register pressure
    #pragma unroll
    for (int half = 0; half < 2; ++half) {
      union { uint32_t u[4]; bf16x8 v; } Ah[4], Al[4];
      #pragma unroll
      for (int r4 = 0; r4 < 4; ++r4) {
        const int r = wr*128 + (half*4 + r4)*16 + lc;
        const int s0 = kg*2;
        const float4 a0 = *(const float4*)(&Ab[cur][r*32 + ((s0    ) ^ (r & 7))*4]);
        const float4 a1 = *(const float4*)(&Ab[cur][r*32 + ((s0 + 1) ^ (r & 7))*4]);
        const float av[8] = {a0.x,a0.y,a0.z,a0.w,a1.x,a1.y,a1.z,a1.w};
        #pragma unroll
        for (int i = 0; i < 4; ++i) {
          const uint32_t b0 = __float_as_uint(av[2*i]), b1 = __float_as_uint(av[2*i+1]);
          Ah[r4].u[i] = (b0 >> 16) | (b1 & 0xFFFF0000u);
          const float f0 = av[2*i]   - __uint_as_float(b0 & 0xFFFF0000u);
          const float f1 = av[2*i+1] - __uint_as_float(b1 & 0xFFFF0000u);
          Al[r4].u[i] = (__float_as_uint(f0) >> 16) | (__float_as_uint(f1) & 0xFFFF0000u);
        }
      }
      #pragma unroll
      for (int r4 = 0; r4 < 4; ++r4)
        #pragma unroll
        for (int cf = 0; cf < 4; ++cf) {
          const int rf = half*4 + r4;
          acc[rf][cf] = __builtin_amdgcn_mfma_f32_16x16x32_bf16(Ah[r4].v, fbh[cf], acc[rf][cf], 0, 0, 0);
          acc[rf][cf] = __builtin_amdgcn_mfma_f32_16x16x32_bf16(Al[r4].v, fbh[cf], acc[rf][cf], 0, 0, 0);
          acc[rf][cf] = __builtin_amdgcn_mfma_f32_16x16x32_bf16(Ah[r4].v, fbl[cf], acc[rf][cf], 0, 0, 0);
        }
    }
    // Nyquist dots stream the f32 A tile (exact, overlaps MFMA pipe)
    if (nyq) {
      #pragma unroll
      for (int j = 0; j < 8; ++j) {
        const float4 av = *(const float4*)(&Ab[cur][nr*32 + (j ^ (nr & 7))*4]);
        const float4 m4 = *(const float4*)(wmag + kt*32 + j*4);
        const float4 p4 = *(const float4*)(wph  + kt*32 + j*4);
        dm = fmaf(av.x,m4.x,fmaf(av.y,m4.y,fmaf(av.z,m4.z,fmaf(av.w,m4.w,dm))));
        dp = fmaf(av.x,p4.x,fmaf(av.y,p4.y,fmaf(av.z,p4.z,fmaf(av.w,p4.w,dp))));
      }
    }
    __syncthreads();      // drains vmcnt (stage done) + lgkm (reads done)
    cur = nxt;
  }

  // Epilogue. C/D 16x16: col = lane&15, row = (lane>>4)*4 + q.
  #pragma unroll
  for (int j = 0; j < 2; ++j) {
    const int p = yb*128 + wc*32 + j*16 + lc;         // pair col, < 512
    const float bm = bias[p], bp = bias[513 + p];
    #pragma unroll
    for (int rf = 0; rf < 8; ++rf) {
      const int rbase = mb*256 + wr*128 + rf*16 + kg*4;
      #pragma unroll
      for (int q = 0; q < 4; ++q) {
        const float sm = acc[rf][j][q] + bm;
        const float sp = acc[rf][2+j][q] + bp;
        const float mag = fminf(__expf(sm), 100.0f);
        float aa = mag * __cosf(sp);
        float bb = mag * __sinf(sp);
        if (p == 0) bb = 0.f;                         // DC imag
        *(float2*)(coeffs + (size_t)(rbase + q) * RS + 2*p) = make_float2(aa, bb);
      }
    }
  }
  if (nyq) {
    const float sm = dm + bias[512];
    const float sp = dp + bias[1025];
    const float mag = fminf(__expf(sm), 100.0f);
    *(float2*)(coeffs + (size_t)(mb*256 + nr) * RS + 1024) =
        make_float2(mag * __cosf(sp), 0.f);           // Nyquist imag = 0
  }
}

// ---------------------------------------------------------------------------
// K2: per-frame irfft(1024) + window (unchanged, verified).
// ---------------------------------------------------------------------------
#define PIDX(s) ((s) + ((s) >> 3))

template<int NS>
__device__ __forceinline__ void stage_fft(const float2* in, float2* out, int l)
{
  float2 v[8];
  #pragma unroll
  for (int r = 0; r < 8; ++r) v[r] = in[PIDX(l + 64*r)];
  if (NS > 1) {
    const float ang = TWO_PI * (float)(l & (NS-1)) / (float)(NS * 8);
    float sn, cs; __sincosf(ang, &sn, &cs);
    const float2 wb = f2(cs, sn);
    float2 cur = wb;
    #pragma unroll
    for (int r = 1; r < 8; ++r) { v[r] = cmul(v[r], cur); cur = cmul(cur, wb); }
  }
  const float2 e0=v[0], e1=v[2], e2=v[4], e3=v[6];
  const float2 o0=v[1], o1=v[3], o2=v[5], o3=v[7];
  float2 a = cadd(e0,e2), b = csub(e0,e2), c = cadd(e1,e3), d = csub(e1,e3);
  const float2 E0 = cadd(a,c), E2 = csub(a,c);
  const float2 E1 = f2(b.x - d.y, b.y + d.x), E3 = f2(b.x + d.y, b.y - d.x);
  a = cadd(o0,o2); b = csub(o0,o2); c = cadd(o1,o3); d = csub(o1,o3);
  const float2 O0 = cadd(a,c), O2 = csub(a,c);
  const float2 O1 = f2(b.x - d.y, b.y + d.x), O3 = f2(b.x + d.y, b.y - d.x);
  const float r2 = 0.70710678118654752f;
  const float2 t0 = O0;
  const float2 t1 = f2(r2*(O1.x - O1.y),  r2*(O1.x + O1.y));
  const float2 t2 = f2(-O2.y, O2.x);
  const float2 t3 = f2(-r2*(O3.x + O3.y), r2*(O3.x - O3.y));
  float2 X[8];
  X[0]=cadd(E0,t0); X[4]=csub(E0,t0);
  X[1]=cadd(E1,t1); X[5]=csub(E1,t1);
  X[2]=cadd(E2,t2); X[6]=csub(E2,t2);
  X[3]=cadd(E3,t3); X[7]=csub(E3,t3);
  const int idxD = (l / NS) * (NS * 8) + (l & (NS-1));
  #pragma unroll
  for (int q = 0; q < 8; ++q) out[PIDX(idxD + q*NS)] = X[q];
}

__global__ __launch_bounds__(256) void fft_win(
    const float* coeffs, float* frames, const float* __restrict__ window)
{
  __shared__ float2 bA[4][576];
  __shared__ float2 bB[4][576];
  const int tid = threadIdx.x;
  const int w = tid >> 6, l = tid & 63;
  const size_t f = (size_t)blockIdx.x * 4 + w;
  const float* crow = coeffs + f * RS;
  const float sc = 1.0f / 1024.0f;
  const float a512 = crow[1024];

  #pragma unroll
  for (int j = 0; j < 4; ++j) {
    const int k = 1 + l + 64*j;
    const float2 Ck = *(const float2*)(crow + 2*k);
    const float2 Cq = *(const float2*)(crow + 2*(512-k));
    float sn, cs; __sincosf(TWO_PI * (1.0f/1024.0f) * (float)k, &sn, &cs);
    const float Ex = sc*(Ck.x + Cq.x), Ey = sc*(Ck.y - Cq.y);
    const float Dx = Ck.x - Cq.x,      Dy = Ck.y + Cq.y;
    const float Ox = sc*(cs*Dx - sn*Dy), Oy = sc*(cs*Dy + sn*Dx);
    bA[w][PIDX(k)]     = f2(Ex - Oy, Ey + Ox);
    bA[w][PIDX(512-k)] = f2(Ex + Oy, Ox - Ey);
  }
  if (l == 0) {
    const float a0 = crow[0];
    bA[w][PIDX(0)] = f2(sc*(a0 + a512), sc*(a0 - a512));
  }
  __syncthreads();
  stage_fft<1 >(bA[w], bB[w], l);
  __syncthreads();
  stage_fft<8 >(bB[w], bA[w], l);
  __syncthreads();
  stage_fft<64>(bA[w], bB[w], l);
  __syncthreads();

  float* frow = frames + f * RS;
  #pragma unroll
  for (int j = 0; j < 8; ++j) {
    const int m = l + 64*j;
    const float2 z  = bB[w][PIDX(m)];
    const float2 wv = *(const float2*)(window + 2*m);
    *(float2*)(frow + 2*m) = f2(z.x * wv.x, z.y * wv.y);
  }
}

// ---------------------------------------------------------------------------
// K3: overlap-add gather + normalization (unchanged, verified).
// ---------------------------------------------------------------------------
__global__ __launch_bounds__(256) void gather_out(
    const float* __restrict__ frames, const float* __restrict__ window,
    float* __restrict__ out)
{
  const int idx = blockIdx.x * 256 + threadIdx.x;
  const int b  = idx >> 19;
  const int jj = idx & 524287;
  const int s  = jj + 384;
  int tlo = (s - 768) >> 8; if (tlo < 0) tlo = 0;
  int thi = s >> 8;         if (thi > 2047) thi = 2047;
  float acc = 0.f, nrm = 0.f;
  for (int t = tlo; t <= thi; ++t) {
    const int n = s - (t << 8);
    const float wv = window[n];
    nrm = fmaf(wv, wv, nrm);
    acc += frames[(size_t)(b * 2048 + t) * RS + n];
  }
  out[idx] = acc / nrm;
}

// ---------------------------------------------------------------------------
extern "C" void kernel_launch(void* const* d_in, const int* in_sizes, int n_in,
                              void* d_out, int out_size, void* d_ws, size_t ws_size,
                              hipStream_t stream)
{
  const float* hs     = (const float*)d_in[0];   // (16,2048,512)
  const float* Wm     = (const float*)d_in[1];   // (1026,512)
  const float* bias   = (const float*)d_in[2];   // (1026,)
  const float* window = (const float*)d_in[3];   // (1024,)

  float* buf = (float*)d_ws;                                   // 134,742,016 B
  ushort_t* Bhi = (ushort_t*)((char*)d_ws + 134742016);        // 1,048,576 B
  ushort_t* Blo = Bhi + 4*16*8192;                             // 1,048,576 B

  convert_B<<<256, 256, 0, stream>>>(Wm, Bhi, Blo);
  gemm_mfma<<<512, 512, 0, stream>>>(hs, Bhi, Blo, Wm, bias, buf);
  fft_win<<<FRAMES / 4, 256, 0, stream>>>(buf, buf, window);
  gather_out<<<8388608 / 256, 256, 0, stream>>>(buf, window, (float*)d_out);
}

// Round 5
// 207.838 us; speedup vs baseline: 1.0897x; 1.0092x over previous
//
#include <hip/hip_runtime.h>
#include <hip/hip_fp16.h>
#include <math.h>
#include <stdint.h>

// VocosISTFTHead on MI355X.
//  K0 convert_B : W (1026x512 f32) -> tiled bf16 hi/lo planes [yb4][kt16][r256][k32]
//  K1 convert_A : hs -> bf16 hi/lo planes [m][512] (split precision, trunc hi +
//                 bf16(residual) lo) + Nyquist spec cols (512/1025) in full f32,
//                 written straight into coeffs[.][1024..1025].
//  K2 gemm_mfma : spec = hs @ W.T + b via bf16-split MFMA (Ah*Bh + Al*Bh + Ah*Bl).
//                 256 rows x 128 col-pairs, 8 waves (2M x 4N), 16x16x32 MFMA.
//                 A-only LDS triple-buffer, counted vmcnt(12) (T4 - loads stay in
//                 flight across barriers), B prefetched L2->regs 1 iter ahead.
//                 Zero conversion VALU in the loop. Fused exp/clamp/cos/sin epilogue.
//  K3 fft_win   : 1024-pt real iFFT per frame (512-pt complex Stockham radix-8),
//                 fp16 coeffs in, fp16 windowed frames out.
//  K4 gather_out: deterministic overlap-add gather + window^2 normalization.
// ws (136.45 MB, fits proven 136.84):
//   [0      : 33.55M) Ahi        | later: frames fp16 [0 : 67.1M)
//   [33.55M : 67.11M) Alo        |   (A planes dead before fft writes)
//   [67.11M : 68.16M) Bhi   [68.16M : 69.21M) Blo
//   [69.21M : 136.45M) coeffs fp16 (32768 x 1026 halves)

#define FRAMES  32768
#define TWO_PI  6.283185307179586f

typedef unsigned short ushort_t;
typedef __attribute__((ext_vector_type(8))) short bf16x8;
typedef __attribute__((ext_vector_type(4))) float f32x4;

#define GLDS(gp, lp) __builtin_amdgcn_global_load_lds( \
    (const __attribute__((address_space(1))) void*)(gp), \
    (__attribute__((address_space(3))) void*)(lp), 16, 0, 0)

__device__ __forceinline__ float2 f2(float x, float y){ return make_float2(x,y); }
__device__ __forceinline__ float2 cadd(float2 a, float2 b){ return f2(a.x+b.x, a.y+b.y); }
__device__ __forceinline__ float2 csub(float2 a, float2 b){ return f2(a.x-b.x, a.y-b.y); }
__device__ __forceinline__ float2 cmul(float2 a, float2 b){ return f2(a.x*b.x - a.y*b.y, a.x*b.y + a.y*b.x); }

// ---------------------------------------------------------------------------
// K0: W -> tiled bf16 hi/lo planes. [yb(4)][kt(16)][r(256)][k(32)], linear.
// Tile rows 0-127 = magnitude rows (p = yb*128+r), 128-255 = phase (513+p).
// ---------------------------------------------------------------------------
__global__ __launch_bounds__(256) void convert_B(
    const float* __restrict__ Wm, ushort_t* __restrict__ Bhi, ushort_t* __restrict__ Blo)
{
  const int gid = blockIdx.x * 256 + threadIdx.x;    // 65536 granules of 8 elems
  const int sd = gid & 3;
  const int r  = (gid >> 2) & 255;
  const int kt = (gid >> 10) & 15;
  const int yb = gid >> 14;                          // 0..3
  const int srow = (r < 128) ? (yb*128 + r) : (513 + yb*128 + (r - 128));
  const float* src = Wm + (size_t)srow * 512 + kt*32 + sd*8;
  const float4 a = *(const float4*)src;
  const float4 b = *(const float4*)(src + 4);
  const float v[8] = {a.x,a.y,a.z,a.w,b.x,b.y,b.z,b.w};
  uint32_t hi[4], lo[4];
  #pragma unroll
  for (int i = 0; i < 4; ++i) {
    const uint32_t b0 = __float_as_uint(v[2*i]), b1 = __float_as_uint(v[2*i+1]);
    hi[i] = (b0 >> 16) | (b1 & 0xFFFF0000u);
    const float f0 = v[2*i]   - __uint_as_float(b0 & 0xFFFF0000u);
    const float f1 = v[2*i+1] - __uint_as_float(b1 & 0xFFFF0000u);
    lo[i] = (__float_as_uint(f0) >> 16) | (__float_as_uint(f1) & 0xFFFF0000u);
  }
  const size_t off = (size_t)gid * 8;
  *(uint4*)(Bhi + off) = make_uint4(hi[0], hi[1], hi[2], hi[3]);
  *(uint4*)(Blo + off) = make_uint4(lo[0], lo[1], lo[2], lo[3]);
}

// ---------------------------------------------------------------------------
// K1: hs -> Ahi/Alo bf16 planes + Nyquist pair (full f32 dots) into coeffs.
// Block = 16 rows; thread (r=t>>4, c=t&15) owns 32 elems of row m.
// ---------------------------------------------------------------------------
__global__ __launch_bounds__(256) void convert_A(
    const float* __restrict__ hs, const float* __restrict__ Wm,
    const float* __restrict__ bias, ushort_t* __restrict__ Ahi,
    ushort_t* __restrict__ Alo, __half* __restrict__ coeffs)
{
  const int t = threadIdx.x;
  const int r = t >> 4, c = t & 15;
  const int m = blockIdx.x * 16 + r;
  const float* src = hs + (size_t)m * 512 + c * 32;
  const float* wm  = Wm + (size_t)512  * 512 + c * 32;
  const float* wp  = Wm + (size_t)1025 * 512 + c * 32;

  float v[32];
  #pragma unroll
  for (int i = 0; i < 8; ++i) *(float4*)&v[i*4] = *(const float4*)(src + i*4);

  float dm = 0.f, dp = 0.f;
  #pragma unroll
  for (int i = 0; i < 8; ++i) {
    const float4 a  = *(const float4*)&v[i*4];
    const float4 m4 = *(const float4*)(wm + i*4);
    const float4 p4 = *(const float4*)(wp + i*4);
    dm = fmaf(a.x,m4.x, fmaf(a.y,m4.y, fmaf(a.z,m4.z, fmaf(a.w,m4.w, dm))));
    dp = fmaf(a.x,p4.x, fmaf(a.y,p4.y, fmaf(a.z,p4.z, fmaf(a.w,p4.w, dp))));
  }

  uint32_t hu[16], lu[16];
  #pragma unroll
  for (int i = 0; i < 16; ++i) {
    const uint32_t b0 = __float_as_uint(v[2*i]), b1 = __float_as_uint(v[2*i+1]);
    hu[i] = (b0 >> 16) | (b1 & 0xFFFF0000u);
    const float f0 = v[2*i]   - __uint_as_float(b0 & 0xFFFF0000u);
    const float f1 = v[2*i+1] - __uint_as_float(b1 & 0xFFFF0000u);
    lu[i] = (__float_as_uint(f0) >> 16) | (__float_as_uint(f1) & 0xFFFF0000u);
  }
  ushort_t* dh = Ahi + (size_t)m * 512 + c * 32;
  ushort_t* dl = Alo + (size_t)m * 512 + c * 32;
  #pragma unroll
  for (int q = 0; q < 4; ++q) {
    *(uint4*)(dh + q*8) = make_uint4(hu[4*q], hu[4*q+1], hu[4*q+2], hu[4*q+3]);
    *(uint4*)(dl + q*8) = make_uint4(lu[4*q], lu[4*q+1], lu[4*q+2], lu[4*q+3]);
  }
  // Nyquist dots: reduce over the 16 lanes of this row
  #pragma unroll
  for (int off = 8; off; off >>= 1) {
    dm += __shfl_xor(dm, off, 16);
    dp += __shfl_xor(dp, off, 16);
  }
  if (c == 0) {
    const float sm = dm + bias[512], sp = dp + bias[1025];
    const float mag = fminf(__expf(sm), 100.0f);
    *(__half2*)(coeffs + (size_t)m * 1026 + 1024) =
        __float22half2_rn(make_float2(mag * __cosf(sp), 0.f));
  }
}

// ---------------------------------------------------------------------------
// K2: MFMA GEMM, 256 rows x 128 col-pairs, 512 threads, A-only LDS 3-buffer.
// ---------------------------------------------------------------------------
__global__ __launch_bounds__(512, 2) void gemm_mfma(
    const ushort_t* __restrict__ Ahi, const ushort_t* __restrict__ Bhi,
    const float* __restrict__ bias, __half* __restrict__ coeffs)
{
  __shared__ ushort_t Ab[49152];       // 3 bufs x (2 planes x 256r x 32k) bf16 = 96KB

  const int tid = threadIdx.x;
  const int w = tid >> 6, l = tid & 63;
  const int wr = w >> 2, wc = w & 3;         // wave grid 2M x 4N
  const int lc = l & 15, kg = l >> 4;        // frag row/col, k-octet

  const int bid = blockIdx.x;                // 512 = 8 XCD * 64
  const int swz = (bid & 7) * 64 + (bid >> 3);
  const int mb = swz >> 2, yb = swz & 3;

  // A staging: granule g=(plane,r,sd); LDS linear, source inverse-swizzled
  // (swizzle sl = sd ^ ((r>>1)&3) makes frag ds_read_b128 bank-conflict-free).
  uint32_t pa_off[4], lofs[4];
  #pragma unroll
  for (int ch = 0; ch < 4; ++ch) {
    const int g = ch*512 + tid;
    const int plane = g >> 10, gg = g & 1023;
    const int r2 = gg >> 2, sd = gg & 3;
    lofs[ch] = plane*8192 + r2*32 + sd*8;
    const int sl = sd ^ ((r2 >> 1) & 3);
    pa_off[ch] = plane*16777216u + (uint32_t)(mb*256 + r2)*512 + sl*8;
  }
  // B fragment sources (registers, direct from L2-resident tiled planes)
  uint32_t pb_off[8];
  #pragma unroll
  for (int cf = 0; cf < 4; ++cf) {
    const int rB = ((cf < 2) ? 0 : 128) + wc*32 + (cf & 1)*16 + lc;
    const uint32_t o = (uint32_t)yb*131072u + rB*32 + kg*8;
    pb_off[cf*2+0] = o;              // Bhi
    pb_off[cf*2+1] = o + 524288u;    // Blo (adjacent plane)
  }

  f32x4 acc[8][4];                   // [rf][cf]: cf 0,1 mag; 2,3 phase
  #pragma unroll
  for (int rf = 0; rf < 8; ++rf)
    #pragma unroll
    for (int cf = 0; cf < 4; ++cf)
      #pragma unroll
      for (int q = 0; q < 4; ++q) acc[rf][cf][q] = 0.f;

  const int asl = (kg ^ ((lc >> 1) & 3)) * 8;    // frag k-slot (rf-independent)

#define STAGE_A(KT, AB) do {                                             \
    _Pragma("unroll")                                                    \
    for (int ch = 0; ch < 4; ++ch)                                       \
      GLDS(Ahi + pa_off[ch] + (KT)*32, &Ab[(AB) + lofs[ch]]);            \
  } while (0)

#define LOAD_B(KT, RB) do {                                              \
    _Pragma("unroll")                                                    \
    for (int q8 = 0; q8 < 8; ++q8)                                       \
      RB[q8] = *(const bf16x8*)(Bhi + pb_off[q8] + (KT)*8192);           \
  } while (0)

#define COMPUTE(ABASE, RB) do {                                          \
    _Pragma("unroll")                                                    \
    for (int rf = 0; rf < 8; ++rf) {                                     \
      const int rr = wr*128 + rf*16 + lc;                                \
      const bf16x8 fah = *(const bf16x8*)(&Ab[(ABASE) + rr*32 + asl]);   \
      const bf16x8 fal = *(const bf16x8*)(&Ab[(ABASE) + 8192 + rr*32 + asl]); \
      _Pragma("unroll")                                                  \
      for (int cf = 0; cf < 4; ++cf) {                                   \
        acc[rf][cf] = __builtin_amdgcn_mfma_f32_16x16x32_bf16(fah, RB[cf*2+0], acc[rf][cf], 0,0,0); \
        acc[rf][cf] = __builtin_amdgcn_mfma_f32_16x16x32_bf16(fal, RB[cf*2+0], acc[rf][cf], 0,0,0); \
        acc[rf][cf] = __builtin_amdgcn_mfma_f32_16x16x32_bf16(fah, RB[cf*2+1], acc[rf][cf], 0,0,0); \
      }                                                                  \
    }                                                                    \
  } while (0)

#define WAITV12 asm volatile("s_waitcnt vmcnt(12) lgkmcnt(0)" ::: "memory")
#define WAITV0  asm volatile("s_waitcnt vmcnt(0) lgkmcnt(0)"  ::: "memory")
#define SB      __builtin_amdgcn_s_barrier()
#define SCH0    __builtin_amdgcn_sched_barrier(0)

  // Steady state at iter top: in-flight = [A(kt), A(kt+1), B(kt)] = 16;
  // vmcnt(12) drains exactly A(kt) (oldest 4), keeping 12 loads across the
  // barrier (T4). WAR safe: STAGE target buf was last read at iter kt-1 and
  // all waves passed this barrier after finishing kt-1 (lgkmcnt(0)).
#define ITER(KT, RBC, RBN, LAST) do {                                    \
    if (LAST) { WAITV0; } else { WAITV12; }                              \
    SB; SCH0;                                                            \
    if ((KT) < 14) { STAGE_A((KT)+2, aW); }                              \
    SCH0;                                                                \
    if ((KT) < 15) { LOAD_B((KT)+1, RBN); }                              \
    COMPUTE(aR, RBC);                                                    \
    { const unsigned t_ = aR; aR = aN; aN = aW; aW = t_; }               \
  } while (0)

  bf16x8 rb0[8], rb1[8];
  STAGE_A(0, 0);
  SCH0;
  LOAD_B(0, rb0);
  STAGE_A(1, 16384);
  unsigned aR = 0, aN = 16384, aW = 32768;

  for (int k2 = 0; k2 < 8; ++k2) {
    ITER(2*k2,     rb0, rb1, false);
    ITER(2*k2 + 1, rb1, rb0, k2 == 7);
  }
#undef ITER
#undef STAGE_A
#undef LOAD_B
#undef COMPUTE

  // Epilogue. C/D 16x16: col = lane&15, row = (lane>>4)*4 + q.
  #pragma unroll
  for (int j = 0; j < 2; ++j) {
    const int p = yb*128 + wc*32 + j*16 + lc;          // pair col, < 512
    const float bm = bias[p], bp = bias[513 + p];
    #pragma unroll
    for (int rf = 0; rf < 8; ++rf) {
      const int rbase = mb*256 + wr*128 + rf*16 + kg*4;
      #pragma unroll
      for (int q = 0; q < 4; ++q) {
        const float sm = acc[rf][j][q]   + bm;
        const float sp = acc[rf][2+j][q] + bp;
        const float mag = fminf(__expf(sm), 100.0f);
        float aa = mag * __cosf(sp);
        float bb = mag * __sinf(sp);
        if (p == 0) bb = 0.f;                          // DC imag
        *(__half2*)(coeffs + (size_t)(rbase + q) * 1026 + 2*p) =
            __float22half2_rn(make_float2(aa, bb));
      }
    }
  }
}

// ---------------------------------------------------------------------------
// K3: per-frame irfft(1024) + window. fp16 coeffs in, fp16 frames out.
// ---------------------------------------------------------------------------
#define PIDX(s) ((s) + ((s) >> 3))

template<int NS>
__device__ __forceinline__ void stage_fft(const float2* in, float2* out, int l)
{
  float2 v[8];
  #pragma unroll
  for (int r = 0; r < 8; ++r) v[r] = in[PIDX(l + 64*r)];
  if (NS > 1) {
    const float ang = TWO_PI * (float)(l & (NS-1)) / (float)(NS * 8);
    float sn, cs; __sincosf(ang, &sn, &cs);
    const float2 wb = f2(cs, sn);
    float2 cur = wb;
    #pragma unroll
    for (int r = 1; r < 8; ++r) { v[r] = cmul(v[r], cur); cur = cmul(cur, wb); }
  }
  const float2 e0=v[0], e1=v[2], e2=v[4], e3=v[6];
  const float2 o0=v[1], o1=v[3], o2=v[5], o3=v[7];
  float2 a = cadd(e0,e2), b = csub(e0,e2), c = cadd(e1,e3), d = csub(e1,e3);
  const float2 E0 = cadd(a,c), E2 = csub(a,c);
  const float2 E1 = f2(b.x - d.y, b.y + d.x), E3 = f2(b.x + d.y, b.y - d.x);
  a = cadd(o0,o2); b = csub(o0,o2); c = cadd(o1,o3); d = csub(o1,o3);
  const float2 O0 = cadd(a,c), O2 = csub(a,c);
  const float2 O1 = f2(b.x - d.y, b.y + d.x), O3 = f2(b.x + d.y, b.y - d.x);
  const float r2 = 0.70710678118654752f;
  const float2 t0 = O0;
  const float2 t1 = f2(r2*(O1.x - O1.y),  r2*(O1.x + O1.y));
  const float2 t2 = f2(-O2.y, O2.x);
  const float2 t3 = f2(-r2*(O3.x + O3.y), r2*(O3.x - O3.y));
  float2 X[8];
  X[0]=cadd(E0,t0); X[4]=csub(E0,t0);
  X[1]=cadd(E1,t1); X[5]=csub(E1,t1);
  X[2]=cadd(E2,t2); X[6]=csub(E2,t2);
  X[3]=cadd(E3,t3); X[7]=csub(E3,t3);
  const int idxD = (l / NS) * (NS * 8) + (l & (NS-1));
  #pragma unroll
  for (int q = 0; q < 8; ++q) out[PIDX(idxD + q*NS)] = X[q];
}

__global__ __launch_bounds__(256) void fft_win(
    const __half* coeffs, __half* frames, const float* __restrict__ window)
{
  __shared__ float2 bA[4][576];
  __shared__ float2 bB[4][576];
  const int tid = threadIdx.x;
  const int w = tid >> 6, l = tid & 63;
  const size_t f = (size_t)blockIdx.x * 4 + w;
  const __half2* crow = (const __half2*)(coeffs + f * 1026);
  const float sc = 1.0f / 1024.0f;
  const float a512 = __half2float(__low2half(crow[512]));

  #pragma unroll
  for (int j = 0; j < 4; ++j) {
    const int k = 1 + l + 64*j;
    const float2 Ck = __half22float2(crow[k]);
    const float2 Cq = __half22float2(crow[512-k]);
    float sn, cs; __sincosf(TWO_PI * (1.0f/1024.0f) * (float)k, &sn, &cs);
    const float Ex = sc*(Ck.x + Cq.x), Ey = sc*(Ck.y - Cq.y);
    const float Dx = Ck.x - Cq.x,      Dy = Ck.y + Cq.y;
    const float Ox = sc*(cs*Dx - sn*Dy), Oy = sc*(cs*Dy + sn*Dx);
    bA[w][PIDX(k)]     = f2(Ex - Oy, Ey + Ox);
    bA[w][PIDX(512-k)] = f2(Ex + Oy, Ox - Ey);
  }
  if (l == 0) {
    const float a0 = __half2float(__low2half(crow[0]));
    bA[w][PIDX(0)] = f2(sc*(a0 + a512), sc*(a0 - a512));
  }
  __syncthreads();
  stage_fft<1 >(bA[w], bB[w], l);
  __syncthreads();
  stage_fft<8 >(bB[w], bA[w], l);
  __syncthreads();
  stage_fft<64>(bA[w], bB[w], l);
  __syncthreads();

  __half2* frow = (__half2*)(frames + f * 1024);
  #pragma unroll
  for (int j = 0; j < 8; ++j) {
    const int m = l + 64*j;
    const float2 z  = bB[w][PIDX(m)];
    const float2 wv = *(const float2*)(window + 2*m);
    frow[m] = __float22half2_rn(make_float2(z.x * wv.x, z.y * wv.y));
  }
}

// ---------------------------------------------------------------------------
// K4: overlap-add gather + normalization. fp16 frames in, f32 out.
// ---------------------------------------------------------------------------
__global__ __launch_bounds__(256) void gather_out(
    const __half* __restrict__ frames, const float* __restrict__ window,
    float* __restrict__ out)
{
  const int idx = blockIdx.x * 256 + threadIdx.x;
  const int b  = idx >> 19;
  const int jj = idx & 524287;
  const int s  = jj + 384;
  int tlo = (s - 768) >> 8; if (tlo < 0) tlo = 0;
  int thi = s >> 8;         if (thi > 2047) thi = 2047;
  float acc = 0.f, nrm = 0.f;
  for (int t = tlo; t <= thi; ++t) {
    const int n = s - (t << 8);
    const float wv = window[n];
    nrm = fmaf(wv, wv, nrm);
    acc += __half2float(frames[(size_t)(b * 2048 + t) * 1024 + n]);
  }
  out[idx] = acc / nrm;
}

// ---------------------------------------------------------------------------
extern "C" void kernel_launch(void* const* d_in, const int* in_sizes, int n_in,
                              void* d_out, int out_size, void* d_ws, size_t ws_size,
                              hipStream_t stream)
{
  const float* hs     = (const float*)d_in[0];   // (16,2048,512)
  const float* Wm     = (const float*)d_in[1];   // (1026,512)
  const float* bias   = (const float*)d_in[2];   // (1026,)
  const float* window = (const float*)d_in[3];   // (1024,)

  char* base = (char*)d_ws;
  ushort_t* Ahi    = (ushort_t*)base;                     // 33,554,432 B
  ushort_t* Alo    = (ushort_t*)(base + 33554432);        // 33,554,432 B (Ahi+16M elems)
  ushort_t* Bhi    = (ushort_t*)(base + 67108864);        // 1,048,576 B
  ushort_t* Blo    = (ushort_t*)(base + 68157440);        // 1,048,576 B (Bhi+512K elems)
  __half*   coeffs = (__half*)(base + 69206016);          // 67,239,936 B
  __half*   frames = (__half*)base;                       // 67,108,864 B (reuses A planes)
  (void)Alo; (void)Blo;

  convert_B<<<256,  256, 0, stream>>>(Wm, Bhi, Blo);
  convert_A<<<2048, 256, 0, stream>>>(hs, Wm, bias, Ahi, Alo, coeffs);
  gemm_mfma<<<512,  512, 0, stream>>>(Ahi, Bhi, bias, coeffs);
  fft_win<<<FRAMES / 4, 256, 0, stream>>>(coeffs, frames, window);
  gather_out<<<8388608 / 256, 256, 0, stream>>>(frames, window, (float*)d_out);
}